// Round 1
// baseline (383.696 us; speedup 1.0000x reference)
//
#include <hip/hip_runtime.h>
#include <math.h>

// Problem constants (from reference)
#define NH 4
#define HD 64
#define HIDDEN 256
#define BS 32
#define NB 64          // NUM_BLOCKS = MAX_LEN/BS = 2048/32
#define SCALE 0.125f
#define INV_SCALE 8.0f

__device__ __forceinline__ float sigmoidf_(float x) {
    return 1.0f / (1.0f + expf(-x));
}

// Kernel 1: block means of k and v.
// k_cmpT layout: [b][h][d][m]   (coalesced over m for the score phase)
// v_cmpR layout: [b][h][m][d]   (coalesced over d for the o_cmp phase)
__global__ __launch_bounds__(256) void kcmp_kernel(
    const float* __restrict__ k, const float* __restrict__ v,
    const int* __restrict__ x_offsets,
    float* __restrict__ k_cmpT, float* __restrict__ v_cmpR) {
    int wg  = blockIdx.x;          // b*NB + blk
    int b   = wg >> 6;
    int blk = wg & 63;
    int tid = threadIdx.x;         // h*64 + d
    int h = tid >> 6, d = tid & 63;
    int s0   = x_offsets[b];
    int len  = x_offsets[b + 1] - s0;
    int nblk = len >> 5;
    float sum_k = 0.f, sum_v = 0.f;
    if (blk < nblk) {
        const float* kp = k + (size_t)(s0 + blk * BS) * HIDDEN + tid;
        const float* vp = v + (size_t)(s0 + blk * BS) * HIDDEN + tid;
        #pragma unroll
        for (int i = 0; i < BS; ++i) {
            sum_k += kp[(size_t)i * HIDDEN];
            sum_v += vp[(size_t)i * HIDDEN];
        }
        sum_k *= (1.0f / BS);
        sum_v *= (1.0f / BS);
    }
    k_cmpT[(((size_t)(b * NH + h) * HD + d) * NB) + blk] = sum_k;
    v_cmpR[(((size_t)(b * NH + h) * NB + blk) * HD) + d] = sum_v;
}

// Kernel 2: one workgroup (256 threads = 4 waves) per token t.
// Wave h handles head h; lane index = d (and = block index m in the score phase).
__global__ __launch_bounds__(256) void hstu_main_kernel(
    const float* __restrict__ q, const float* __restrict__ k,
    const float* __restrict__ v, const float* __restrict__ u,
    const float* __restrict__ Wg_cmp,
    const int* __restrict__ x_offsets, const int* __restrict__ batch_ids,
    const int* __restrict__ pos_ids,
    const float* __restrict__ k_cmpT, const float* __restrict__ v_cmpR,
    float* __restrict__ out, int T) {
    int t   = blockIdx.x;
    int tid = threadIdx.x;
    int h = tid >> 6, d = tid & 63;
    int b    = batch_ids[t];
    int pos  = pos_ids[t];
    int s0   = x_offsets[b];
    int qblk = pos >> 5;

    float qv = q[(size_t)t * HIDDEN + tid];

    // g = sigmoid(sum_d q[h,d] * Wg_cmp[h,d])  (wave-wide reduction)
    float gsum = qv * Wg_cmp[tid];
    #pragma unroll
    for (int off = 32; off; off >>= 1) gsum += __shfl_xor(gsum, off, 64);
    float g = sigmoidf_(gsum);

    // ---- Compressed scores: lane m = d computes raw_m = q . k_cmp[m] ----
    int m = d;
    const float* kcT = k_cmpT + (size_t)(b * NH + h) * HD * NB;   // [dd][m]
    float raw = 0.f;
    for (int dd = 0; dd < HD; ++dd) {
        float qdd = __shfl(qv, dd, 64);
        raw += qdd * kcT[(size_t)dd * NB + m];
    }
    raw *= SCALE;
    float p = 0.f;
    if (m <= qblk) p = raw * sigmoidf_(raw) * INV_SCALE;   // silu(raw)*INV_SCALE
    float sel = (m == qblk) ? 1.0f : p;

    // ---- top-3 (need ranks 0 and 2 after topk[1::2]=topk[0::2] dedup) ----
    // Key: monotone-uint(value) in high bits, (63-m) in low bits -> max-reduce
    // reproduces jax.lax.top_k order (value desc, index asc).
    unsigned ub = __float_as_uint(sel);
    ub = (ub & 0x80000000u) ? ~ub : (ub | 0x80000000u);
    unsigned long long mykey = ((unsigned long long)ub << 32) | (unsigned)(63 - m);
    int idx0 = 0, idx2 = 0;
    #pragma unroll
    for (int s = 0; s < 3; ++s) {
        unsigned long long kmax = mykey;
        #pragma unroll
        for (int off = 32; off; off >>= 1) {
            unsigned long long o = __shfl_xor(kmax, off, 64);
            if (o > kmax) kmax = o;
        }
        int im = 63 - (int)(kmax & 0xFFFFFFFFull);
        if (s == 0) idx0 = im;
        if (s == 2) idx2 = im;
        if (m == im) mykey = 0ull;   // remove winner
    }

    // ---- o_cmp: lane d accumulates sum_m p_m * v_cmp[m][d], then * g ----
    const float* vcR = v_cmpR + (size_t)(b * NH + h) * NB * HD;   // [m][d]
    float oc = 0.f;
    for (int mm = 0; mm <= qblk; ++mm) {
        float pm = __shfl(p, mm, 64);
        oc += pm * vcR[(size_t)mm * HD + d];
    }
    oc *= g;

    // ---- o_slc: two selected blocks, each weighted x2 ----
    float os = 0.f;
    int blocks[2] = { idx0, idx2 };
    #pragma unroll
    for (int s = 0; s < 2; ++s) {
        int base = blocks[s] * BS;
        for (int i = 0; i < BS; ++i) {
            int pis = base + i;
            if (pis > pos) break;            // uniform across wave; causal cut
            int tgt = s0 + pis;
            if (tgt > T - 1) tgt = T - 1;
            float kvv = k[(size_t)tgt * HIDDEN + h * HD + d];
            float sc = qv * kvv;
            #pragma unroll
            for (int off = 32; off; off >>= 1) sc += __shfl_xor(sc, off, 64);
            sc *= SCALE;
            float pp = sc * sigmoidf_(sc) * INV_SCALE * 2.0f;  // x2: dup topk
            os += pp * v[(size_t)tgt * HIDDEN + h * HD + d];
        }
    }

    // ---- dual LayerNorm over 256 dims + gate by u, sum ----
    __shared__ float red[NH][4];
    float sc_ = oc, sc2 = oc * oc, ss_ = os, ss2 = os * os;
    #pragma unroll
    for (int off = 32; off; off >>= 1) {
        sc_ += __shfl_xor(sc_, off, 64);
        sc2 += __shfl_xor(sc2, off, 64);
        ss_ += __shfl_xor(ss_, off, 64);
        ss2 += __shfl_xor(ss2, off, 64);
    }
    if (d == 0) { red[h][0] = sc_; red[h][1] = sc2; red[h][2] = ss_; red[h][3] = ss2; }
    __syncthreads();
    float tc = 0.f, tc2 = 0.f, ts = 0.f, ts2 = 0.f;
    #pragma unroll
    for (int w = 0; w < NH; ++w) {
        tc += red[w][0]; tc2 += red[w][1]; ts += red[w][2]; ts2 += red[w][3];
    }
    float muc  = tc  * (1.0f / HIDDEN);
    float varc = tc2 * (1.0f / HIDDEN) - muc * muc;
    float mus  = ts  * (1.0f / HIDDEN);
    float vars = ts2 * (1.0f / HIDDEN) - mus * mus;
    float uval = u[(size_t)t * HIDDEN + tid];
    float outv = (oc - muc) * rsqrtf(varc + 1e-6f) * uval
               + (os - mus) * rsqrtf(vars + 1e-6f) * uval;
    out[(size_t)t * HIDDEN + tid] = outv;
}

extern "C" void kernel_launch(void* const* d_in, const int* in_sizes, int n_in,
                              void* d_out, int out_size, void* d_ws, size_t ws_size,
                              hipStream_t stream) {
    const float* q      = (const float*)d_in[0];
    const float* k      = (const float*)d_in[1];
    const float* v      = (const float*)d_in[2];
    const float* u      = (const float*)d_in[3];
    const float* Wg_cmp = (const float*)d_in[4];
    // d_in[5] = Wg_slc: dead code in the reference (computed, never used)
    const int* x_offsets = (const int*)d_in[6];
    const int* batch_ids = (const int*)d_in[7];
    const int* pos_ids   = (const int*)d_in[8];

    int T = in_sizes[0] / HIDDEN;
    int B = in_sizes[6] - 1;

    float* k_cmpT = (float*)d_ws;                       // B*NH*HD*NB floats
    float* v_cmpR = k_cmpT + (size_t)B * NH * HD * NB;  // B*NH*NB*HD floats

    kcmp_kernel<<<B * NB, 256, 0, stream>>>(k, v, x_offsets, k_cmpT, v_cmpR);
    hstu_main_kernel<<<T, 256, 0, stream>>>(q, k, v, u, Wg_cmp,
                                            x_offsets, batch_ids, pos_ids,
                                            k_cmpT, v_cmpR, (float*)d_out, T);
}

// Round 4
// 377.185 us; speedup vs baseline: 1.0173x; 1.0173x over previous
//
#include <hip/hip_runtime.h>
#include <math.h>

// Problem constants (from reference)
#define NH 4
#define HD 64
#define HIDDEN 256
#define BS 32
#define NB 64          // NUM_BLOCKS = MAX_LEN/BS = 2048/32
#define SCALE 0.125f
#define INV_SCALE 8.0f

__device__ __forceinline__ float fast_sigmoid(float x) {
    return 1.0f / (1.0f + __expf(-x));
}

// Kernel 1: block means. K means in DOUBLE (selection path must be f64-exact
// vs the np reference to avoid top-k tie flips); V means in float.
// k_cmpT64 layout: [b][h][d][m] (coalesced over m for the score phase)
// v_cmpR   layout: [b][h][m][d] (coalesced over d for the o_cmp phase)
__global__ __launch_bounds__(256) void kcmp_kernel(
    const float* __restrict__ k, const float* __restrict__ v,
    const int* __restrict__ x_offsets,
    double* __restrict__ k_cmpT64, float* __restrict__ v_cmpR) {
    int wg  = blockIdx.x;          // b*NB + blk
    int b   = wg >> 6;
    int blk = wg & 63;
    int tid = threadIdx.x;
    int c4  = tid & 63;            // float4 column (64 per 256-float row)
    int rg  = tid >> 6;            // row group: rows rg*8 .. rg*8+7
    int s0   = x_offsets[b];
    int len  = x_offsets[b + 1] - s0;
    int nblk = len >> 5;
    double skx = 0, sky = 0, skz = 0, skw = 0;
    float4 sv = {0.f, 0.f, 0.f, 0.f};
    if (blk < nblk) {
        const float4* kp = (const float4*)(k + (size_t)(s0 + blk * BS + rg * 8) * HIDDEN) + c4;
        const float4* vp = (const float4*)(v + (size_t)(s0 + blk * BS + rg * 8) * HIDDEN) + c4;
        #pragma unroll
        for (int i = 0; i < 8; ++i) {
            float4 a = kp[i * 64];     // advance one row (64 float4) per step
            float4 c = vp[i * 64];
            skx += (double)a.x; sky += (double)a.y;
            skz += (double)a.z; skw += (double)a.w;
            sv.x += c.x; sv.y += c.y; sv.z += c.z; sv.w += c.w;
        }
    }
    __shared__ double lk[4][64][4];
    __shared__ float4 lv[4][64];
    lk[rg][c4][0] = skx; lk[rg][c4][1] = sky;
    lk[rg][c4][2] = skz; lk[rg][c4][3] = skw;
    lv[rg][c4] = sv;
    __syncthreads();
    if (rg == 0) {
        double rk[4];
        #pragma unroll
        for (int j = 0; j < 4; ++j)
            rk[j] = (lk[0][c4][j] + lk[1][c4][j] + lk[2][c4][j] + lk[3][c4][j]) * (1.0 / BS);
        float4 b0 = lv[0][c4], b1 = lv[1][c4], b2 = lv[2][c4], b3 = lv[3][c4];
        float4 rv;
        rv.x = (b0.x + b1.x + b2.x + b3.x) * (1.0f / BS);
        rv.y = (b0.y + b1.y + b2.y + b3.y) * (1.0f / BS);
        rv.z = (b0.z + b1.z + b2.z + b3.z) * (1.0f / BS);
        rv.w = (b0.w + b1.w + b2.w + b3.w) * (1.0f / BS);
        int h  = c4 >> 4;            // (4*c4)>>6
        int d0 = (c4 & 15) * 4;      // (4*c4)&63
        double* kt = k_cmpT64 + ((size_t)(b * NH + h) * HD) * NB + blk;
        #pragma unroll
        for (int j = 0; j < 4; ++j) kt[(size_t)(d0 + j) * NB] = rk[j];
        *(float4*)(v_cmpR + ((size_t)(b * NH + h) * NB + blk) * HD + d0) = rv;
    }
}

// Kernel 2: one workgroup (256 threads = 4 waves) per token t.
// Wave h handles head h; lane = d (= block index m in the cmp-score phase,
// = (sel_block, pos_in_block) in the slc-score phase).
__global__ __launch_bounds__(256) void hstu_main_kernel(
    const float* __restrict__ q, const float* __restrict__ k,
    const float* __restrict__ v, const float* __restrict__ u,
    const float* __restrict__ Wg_cmp,
    const int* __restrict__ x_offsets, const int* __restrict__ batch_ids,
    const int* __restrict__ pos_ids,
    const double* __restrict__ k_cmpT64, const float* __restrict__ v_cmpR,
    float* __restrict__ out, int T) {
    int t   = blockIdx.x;
    int tid = threadIdx.x;
    int h = __builtin_amdgcn_readfirstlane(tid >> 6);  // wave-uniform -> SGPR
    int d = tid & 63;
    int b    = batch_ids[t];      // t uniform -> scalar loads
    int pos  = pos_ids[t];
    int s0   = x_offsets[b];
    int qblk = pos >> 5;

    const float* qrow = q + (size_t)t * HIDDEN + h * HD;  // uniform base -> s_load
    float qv = qrow[d];

    // g = sigmoid(q[h] . Wg_cmp[h])  (wave reduction)
    float gsum = qv * Wg_cmp[h * HD + d];
    #pragma unroll
    for (int off = 32; off; off >>= 1) gsum += __shfl_xor(gsum, off, 64);
    float g = fast_sigmoid(gsum);

    // ---- Compressed scores in f64 (selection must be tie-exact vs np ref) ----
    const double* kcT = k_cmpT64 + (size_t)(b * NH + h) * HD * NB;   // [dd][m]
    double raw = 0.0;
    #pragma unroll 8
    for (int dd = 0; dd < HD; ++dd) {
        raw += (double)qrow[dd] * kcT[dd * NB + d];
    }
    raw *= 0.125;
    double p64 = 0.0;
    if (d <= qblk) p64 = raw / (1.0 + exp(-raw)) * 8.0;   // silu(raw)*INV_SCALE
    double sel = (d == qblk) ? 1.0 : p64;

    // ---- top-3 (need ranks 0 and 2 after topk[1::2]=topk[0::2] dedup) ----
    // Order: value desc, index asc (jax.lax.top_k). (key,idx) pair reduction.
    long long sbits = __double_as_longlong(sel);
    unsigned long long mykey = (unsigned long long)sbits;
    mykey = (sbits < 0) ? ~mykey : (mykey | 0x8000000000000000ull);
    int idx0 = 0, idx2 = 0;
    #pragma unroll
    for (int s = 0; s < 3; ++s) {
        unsigned long long bk = mykey;
        int bi = d;
        #pragma unroll
        for (int off = 32; off; off >>= 1) {
            unsigned long long ok = __shfl_xor(bk, off, 64);
            int oi = __shfl_xor(bi, off, 64);
            if (ok > bk || (ok == bk && oi < bi)) { bk = ok; bi = oi; }
        }
        if (s == 0) idx0 = bi;
        if (s == 2) idx2 = bi;
        if (d == bi) mykey = 0ull;   // remove winner (0 < any finite key)
    }
    idx0 = __builtin_amdgcn_readfirstlane(idx0);   // uniform -> scalar
    idx2 = __builtin_amdgcn_readfirstlane(idx2);

    float p = (float)p64;

    // ---- o_cmp: lane d accumulates sum_m p_m * v_cmp[m][d], then * g ----
    const float* vcR = v_cmpR + (size_t)(b * NH + h) * NB * HD + d;   // [m][d]
    float oc = 0.f;
    #pragma unroll 4
    for (int mm = 0; mm <= qblk; ++mm) {       // qblk uniform -> uniform bound
        float pm = __shfl(p, mm, 64);
        oc += pm * vcR[mm * HD];
    }
    oc *= g;

    // ---- o_slc scores: lane l = (sel_blk s, pos i); stream own K row ----
    int s_sel = d >> 5;
    int i_sel = d & 31;
    int blk_l = s_sel ? idx2 : idx0;
    int pis   = blk_l * BS + i_sel;
    int tgt   = s0 + pis;
    if (tgt > T - 1) tgt = T - 1;
    const float4* krow = (const float4*)(k + (size_t)tgt * HIDDEN + h * HD);
    float sc = 0.f;
    #pragma unroll
    for (int j = 0; j < 16; ++j) {
        float4 kk = krow[j];
        sc += qrow[4*j+0] * kk.x + qrow[4*j+1] * kk.y
            + qrow[4*j+2] * kk.z + qrow[4*j+3] * kk.w;
    }
    sc *= SCALE;
    float pl = (pis <= pos) ? sc * fast_sigmoid(sc) * (INV_SCALE * 2.0f) : 0.f;

    // ---- o_slc accumulate: uniform loop bounds, coalesced V rows ----
    float os = 0.f;
    #pragma unroll
    for (int s = 0; s < 2; ++s) {
        int blkb  = s ? idx2 : idx0;
        int nval  = pos - blkb * BS + 1;
        if (nval > BS) nval = BS;
        if (nval <= 0) continue;                 // uniform branch
        const float* vrow = v + (size_t)(s0 + blkb * BS) * HIDDEN + h * HD + d;
        #pragma unroll 4
        for (int i = 0; i < nval; ++i) {
            float pm = __shfl(pl, s * 32 + i, 64);
            os += pm * vrow[i * HIDDEN];
        }
    }

    // ---- dual LayerNorm over 256 dims + gate by u, sum ----
    __shared__ float red[NH][4];
    float sc_ = oc, sc2 = oc * oc, ss_ = os, ss2 = os * os;
    #pragma unroll
    for (int off = 32; off; off >>= 1) {
        sc_ += __shfl_xor(sc_, off, 64);
        sc2 += __shfl_xor(sc2, off, 64);
        ss_ += __shfl_xor(ss_, off, 64);
        ss2 += __shfl_xor(ss2, off, 64);
    }
    if (d == 0) { red[h][0] = sc_; red[h][1] = sc2; red[h][2] = ss_; red[h][3] = ss2; }
    __syncthreads();
    float tc = 0.f, tc2 = 0.f, ts = 0.f, ts2 = 0.f;
    #pragma unroll
    for (int w = 0; w < NH; ++w) {
        tc += red[w][0]; tc2 += red[w][1]; ts += red[w][2]; ts2 += red[w][3];
    }
    float muc  = tc  * (1.0f / HIDDEN);
    float varc = tc2 * (1.0f / HIDDEN) - muc * muc;
    float mus  = ts  * (1.0f / HIDDEN);
    float vars = ts2 * (1.0f / HIDDEN) - mus * mus;
    float uval = u[(size_t)t * HIDDEN + tid];
    float outv = (oc - muc) * rsqrtf(varc + 1e-6f) * uval
               + (os - mus) * rsqrtf(vars + 1e-6f) * uval;
    out[(size_t)t * HIDDEN + tid] = outv;
}

extern "C" void kernel_launch(void* const* d_in, const int* in_sizes, int n_in,
                              void* d_out, int out_size, void* d_ws, size_t ws_size,
                              hipStream_t stream) {
    const float* q      = (const float*)d_in[0];
    const float* k      = (const float*)d_in[1];
    const float* v      = (const float*)d_in[2];
    const float* u      = (const float*)d_in[3];
    const float* Wg_cmp = (const float*)d_in[4];
    // d_in[5] = Wg_slc: dead code in the reference (computed, never used)
    const int* x_offsets = (const int*)d_in[6];
    const int* batch_ids = (const int*)d_in[7];
    const int* pos_ids   = (const int*)d_in[8];

    int T = in_sizes[0] / HIDDEN;
    int B = in_sizes[6] - 1;

    double* k_cmpT64 = (double*)d_ws;                        // B*NH*HD*NB doubles (1 MB)
    float*  v_cmpR   = (float*)(k_cmpT64 + (size_t)B * NH * HD * NB);  // B*NH*NB*HD floats

    kcmp_kernel<<<B * NB, 256, 0, stream>>>(k, v, x_offsets, k_cmpT64, v_cmpR);
    hstu_main_kernel<<<T, 256, 0, stream>>>(q, k, v, u, Wg_cmp,
                                            x_offsets, batch_ids, pos_ids,
                                            k_cmpT64, v_cmpR, (float*)d_out, T);
}